// Round 1
// baseline (49.511 us; speedup 1.0000x reference)
//
#include <hip/hip_runtime.h>
#include <math.h>

#define BB 384
#define BITS 128
#define NCLS 80
#define NW 3  // 80 bits -> 3 x uint32

// One block per row r. Computes ip[r,:], pos mask, pair loss for row r.
__global__ __launch_bounds__(256) void row_kernel(
    const float* __restrict__ u,
    const int* __restrict__ y,
    float* __restrict__ contrib,   // [BB] row_loss * row_valid
    float* __restrict__ valid)     // [BB] 1.0 if row valid
{
    const int r = blockIdx.x;
    const int tid = threadIdx.x;

    __shared__ float ur[BITS];          // u[r, :]
    __shared__ float a[BB];             // ip[r, :]
    __shared__ float p[BB];             // pos mask (1.0 / 0.0)
    __shared__ unsigned int yw[BB][NW]; // bit-packed labels
    __shared__ float red[256];
    __shared__ int npos_s;

    if (tid < BITS) ur[tid] = u[r * BITS + tid];
    if (tid == 0) npos_s = 0;

    // cooperatively bit-pack all label rows (L2-resident, cheap)
    for (int i = tid; i < BB; i += 256) {
        unsigned int w0 = 0, w1 = 0, w2 = 0;
        const int* yi = y + i * NCLS;
        #pragma unroll
        for (int c = 0; c < 32; ++c) w0 |= (yi[c]      ? 1u : 0u) << c;
        #pragma unroll
        for (int c = 0; c < 32; ++c) w1 |= (yi[32 + c] ? 1u : 0u) << c;
        #pragma unroll
        for (int c = 0; c < 16; ++c) w2 |= (yi[64 + c] ? 1u : 0u) << c;
        yw[i][0] = w0; yw[i][1] = w1; yw[i][2] = w2;
    }
    __syncthreads();

    const unsigned int yr0 = yw[r][0], yr1 = yw[r][1], yr2 = yw[r][2];

    int local_pos = 0;
    for (int i = tid; i < BB; i += 256) {
        // a[i] = dot(u[r], u[i])
        float acc = 0.f;
        const float* ui = u + i * BITS;
        #pragma unroll 8
        for (int k = 0; k < BITS; k += 4) {
            float4 v = *reinterpret_cast<const float4*>(ui + k);
            acc += ur[k] * v.x + ur[k + 1] * v.y + ur[k + 2] * v.z + ur[k + 3] * v.w;
        }
        a[i] = acc;
        unsigned int s = (yr0 & yw[i][0]) | (yr1 & yw[i][1]) | (yr2 & yw[i][2]);
        p[i] = (s != 0u) ? 1.0f : 0.0f;
        local_pos += (s != 0u) ? 1 : 0;
    }
    if (local_pos) atomicAdd(&npos_s, local_pos);  // int sum: order-independent
    __syncthreads();

    const int n_pos = npos_s;
    const int n_neg = BB - n_pos;
    const float pair_count = (float)n_pos * (float)n_neg;

    float sum = 0.f;
    if (n_pos > 0 && n_neg > 0) {
        for (int i = 0; i < BB; ++i) {
            if (p[i] == 0.f) continue;           // block-uniform skip
            const float ai = a[i] - 0.5f;
            for (int j = tid; j < BB; j += 256) {
                if (p[j] != 0.f) continue;       // j must be negative
                float t = ai - a[j];
                t = fminf(fmaxf(t, -100.f), 50.f);
                // softplus(-t) = max(-t,0) + log1p(exp(-|t|))
                sum += fmaxf(-t, 0.f) + log1pf(expf(-fabsf(t)));
            }
        }
    }

    // deterministic block tree reduce
    red[tid] = sum;
    __syncthreads();
    for (int s = 128; s > 0; s >>= 1) {
        if (tid < s) red[tid] += red[tid + s];
        __syncthreads();
    }
    if (tid == 0) {
        const bool v = pair_count > 0.f;
        contrib[r] = v ? (red[0] / pair_count) : 0.f;
        valid[r]   = v ? 1.f : 0.f;
    }
}

// Single block: final deterministic reduction of loss1 + loss2.
__global__ __launch_bounds__(256) void final_kernel(
    const float* __restrict__ u,
    const float* __restrict__ contrib,
    const float* __restrict__ valid,
    float* __restrict__ out)
{
    const int tid = threadIdx.x;
    __shared__ float r1[256], r2[256], rc[256];

    float s1 = 0.f, c = 0.f;
    for (int r = tid; r < BB; r += 256) { s1 += contrib[r]; c += valid[r]; }

    float s2 = 0.f;
    for (int k = tid; k < BB * BITS; k += 256) {
        float v = u[k];
        float sg = (v > 0.f) ? 1.f : ((v < 0.f) ? -1.f : 0.f);
        float d = v - sg;
        s2 += d * d;
    }

    r1[tid] = s1; r2[tid] = s2; rc[tid] = c;
    __syncthreads();
    for (int s = 128; s > 0; s >>= 1) {
        if (tid < s) { r1[tid] += r1[tid + s]; r2[tid] += r2[tid + s]; rc[tid] += rc[tid + s]; }
        __syncthreads();
    }
    if (tid == 0) {
        const float count = rc[0];
        const float loss1 = (count > 0.f) ? (r1[0] / fmaxf(count, 1.f)) : 0.f;
        const float loss2 = 0.1f * r2[0] / (float)(BB * BITS);
        out[0] = loss1 + loss2;
    }
}

extern "C" void kernel_launch(void* const* d_in, const int* in_sizes, int n_in,
                              void* d_out, int out_size, void* d_ws, size_t ws_size,
                              hipStream_t stream) {
    const float* u = (const float*)d_in[0];
    const int*   y = (const int*)d_in[1];
    float* out = (float*)d_out;

    float* contrib = (float*)d_ws;            // BB floats
    float* valid   = contrib + BB;            // BB floats

    row_kernel<<<BB, 256, 0, stream>>>(u, y, contrib, valid);
    final_kernel<<<1, 256, 0, stream>>>(u, contrib, valid, out);
}

// Round 2
// 28.948 us; speedup vs baseline: 1.7104x; 1.7104x over previous
//
#include <hip/hip_runtime.h>
#include <math.h>

#define BB 384
#define BITS 128
#define NCLS 80
#define NW 3  // 80 bits -> 3 x uint32

// --- Kernel 0: bit-pack labels once. 1 block, 384 threads, ~2 us. ---
__global__ __launch_bounds__(384) void pack_kernel(
    const int* __restrict__ y,
    unsigned int* __restrict__ yw)   // [BB*NW]
{
    const int i = threadIdx.x;
    if (i < BB) {
        const int* yi = y + i * NCLS;
        unsigned int w0 = 0, w1 = 0, w2 = 0;
        #pragma unroll
        for (int c = 0; c < 32; ++c) w0 |= (yi[c]      ? 1u : 0u) << c;
        #pragma unroll
        for (int c = 0; c < 32; ++c) w1 |= (yi[32 + c] ? 1u : 0u) << c;
        #pragma unroll
        for (int c = 0; c < 16; ++c) w2 |= (yi[64 + c] ? 1u : 0u) << c;
        yw[i * NW + 0] = w0;
        yw[i * NW + 1] = w1;
        yw[i * NW + 2] = w2;
    }
}

// --- Kernel 1: one block per row r. ip[r,:], mask, pair loss, loss2 partial. ---
__global__ __launch_bounds__(256) void row_kernel(
    const float* __restrict__ u,
    const unsigned int* __restrict__ yw,  // [BB*NW] packed labels
    float* __restrict__ contrib,          // [BB]
    float* __restrict__ valid,            // [BB]
    float* __restrict__ l2part)           // [BB]
{
    const int r = blockIdx.x;
    const int tid = threadIdx.x;

    __shared__ float ur[BITS];
    __shared__ float a[BB];
    __shared__ float p[BB];
    __shared__ unsigned int ywsh[BB * NW];
    __shared__ float red[256], red2[256];
    __shared__ int npos_s;

    if (tid < BITS) ur[tid] = u[r * BITS + tid];
    if (tid == 0) npos_s = 0;
    for (int idx = tid; idx < BB * NW; idx += 256) ywsh[idx] = yw[idx];
    __syncthreads();

    const unsigned int yr0 = ywsh[r * NW + 0];
    const unsigned int yr1 = ywsh[r * NW + 1];
    const unsigned int yr2 = ywsh[r * NW + 2];

    int local_pos = 0;
    for (int i = tid; i < BB; i += 256) {
        float acc = 0.f;
        const float* ui = u + i * BITS;
        #pragma unroll 8
        for (int k = 0; k < BITS; k += 4) {
            float4 v = *reinterpret_cast<const float4*>(ui + k);
            acc += ur[k] * v.x + ur[k + 1] * v.y + ur[k + 2] * v.z + ur[k + 3] * v.w;
        }
        a[i] = acc;
        unsigned int s = (yr0 & ywsh[i * NW + 0]) | (yr1 & ywsh[i * NW + 1]) |
                         (yr2 & ywsh[i * NW + 2]);
        p[i] = (s != 0u) ? 1.0f : 0.0f;
        local_pos += (s != 0u) ? 1 : 0;
    }
    if (local_pos) atomicAdd(&npos_s, local_pos);  // int: order-independent
    __syncthreads();

    const int n_pos = npos_s;
    const int n_neg = BB - n_pos;
    const float pair_count = (float)n_pos * (float)n_neg;

    float sum = 0.f;
    if (n_pos > 0 && n_neg > 0) {
        for (int i = 0; i < BB; ++i) {
            if (p[i] == 0.f) continue;           // block-uniform skip
            const float ai = a[i] - 0.5f;
            for (int j = tid; j < BB; j += 256) {
                if (p[j] != 0.f) continue;
                float t = ai - a[j];
                t = fminf(fmaxf(t, -100.f), 50.f);
                sum += fmaxf(-t, 0.f) + log1pf(expf(-fabsf(t)));  // softplus(-t)
            }
        }
    }

    // loss2 partial for this row: u[r,:] is already in ur[]
    float s2 = 0.f;
    if (tid < BITS) {
        float v = ur[tid];
        float sg = (v > 0.f) ? 1.f : ((v < 0.f) ? -1.f : 0.f);
        float d = v - sg;
        s2 = d * d;
    }

    red[tid] = sum; red2[tid] = s2;
    __syncthreads();
    for (int s = 128; s > 0; s >>= 1) {
        if (tid < s) { red[tid] += red[tid + s]; red2[tid] += red2[tid + s]; }
        __syncthreads();
    }
    if (tid == 0) {
        const bool v = pair_count > 0.f;
        contrib[r] = v ? (red[0] / pair_count) : 0.f;
        valid[r]   = v ? 1.f : 0.f;
        l2part[r]  = red2[0];
    }
}

// --- Kernel 2: tiny final reduction over 3x384 floats. ---
__global__ __launch_bounds__(256) void final_kernel(
    const float* __restrict__ contrib,
    const float* __restrict__ valid,
    const float* __restrict__ l2part,
    float* __restrict__ out)
{
    const int tid = threadIdx.x;
    __shared__ float r1[256], r2[256], rc[256];

    float s1 = 0.f, s2 = 0.f, c = 0.f;
    for (int r = tid; r < BB; r += 256) {
        s1 += contrib[r]; s2 += l2part[r]; c += valid[r];
    }

    r1[tid] = s1; r2[tid] = s2; rc[tid] = c;
    __syncthreads();
    for (int s = 128; s > 0; s >>= 1) {
        if (tid < s) { r1[tid] += r1[tid + s]; r2[tid] += r2[tid + s]; rc[tid] += rc[tid + s]; }
        __syncthreads();
    }
    if (tid == 0) {
        const float count = rc[0];
        const float loss1 = (count > 0.f) ? (r1[0] / fmaxf(count, 1.f)) : 0.f;
        const float loss2 = 0.1f * r2[0] / (float)(BB * BITS);
        out[0] = loss1 + loss2;
    }
}

extern "C" void kernel_launch(void* const* d_in, const int* in_sizes, int n_in,
                              void* d_out, int out_size, void* d_ws, size_t ws_size,
                              hipStream_t stream) {
    const float* u = (const float*)d_in[0];
    const int*   y = (const int*)d_in[1];
    float* out = (float*)d_out;

    float* contrib = (float*)d_ws;                       // BB floats
    float* valid   = contrib + BB;                       // BB floats
    float* l2part  = valid + BB;                         // BB floats
    unsigned int* yw = (unsigned int*)(l2part + BB);     // BB*NW words

    pack_kernel<<<1, 384, 0, stream>>>(y, yw);
    row_kernel<<<BB, 256, 0, stream>>>(u, yw, contrib, valid, l2part);
    final_kernel<<<1, 256, 0, stream>>>(contrib, valid, l2part, out);
}